// Round 18
// baseline (4529.826 us; speedup 1.0000x reference)
//
#include <hip/hip_runtime.h>
#include <cstdint>
#include <cstddef>

// Problem dims
#define NT   256     // T
#define NB   64      // B
#define XD   128
#define HD   1024
#define ZD   128
#define H3   3072
#define TBM  16384   // T*B

typedef __attribute__((ext_vector_type(8))) short bf16x8;
typedef __attribute__((ext_vector_type(4))) float f32x4;
typedef __attribute__((ext_vector_type(4))) unsigned int u32x4;

__device__ __forceinline__ unsigned short f2bf(float f){
  unsigned int u = __float_as_uint(f);
  u += 0x7fffu + ((u >> 16) & 1u);
  return (unsigned short)(u >> 16);
}
__device__ __forceinline__ float bf2f(unsigned short h){
  return __uint_as_float(((unsigned int)h) << 16);
}

template<int N>
__device__ __forceinline__ void vwait(){
  asm volatile("s_waitcnt vmcnt(%0)" :: "i"(N) : "memory");
  __builtin_amdgcn_sched_barrier(0);
}

// async global->LDS, 16B per lane; dest = wave-uniform base + lane*16
__device__ __forceinline__ void gload_lds16(const void* g, void* l){
  __builtin_amdgcn_global_load_lds((const __attribute__((address_space(1))) void*)g,
                                   (__attribute__((address_space(3))) void*)l, 16, 0, 0);
}

// fast gates
__device__ __forceinline__ float fsigmoid(float x){
  return 1.f / (1.f + __expf(-x));
}
__device__ __forceinline__ float ftanh(float x){
  float xc = fminf(fmaxf(x, -15.f), 15.f);
  float e = __expf(2.f * xc);
  return (e - 1.f) / (e + 1.f);
}

// Reader: wave0 lane l polls block l's FOUR per-wave tags (separate 128B sectors,
// dword offsets l*128 + {0,32,64,96}), 2-deep group ping-pong so one group is always
// in flight. Drain vmcnt(0) before return (r12 lesson: in-flight loads' dest VGPRs
// get reused after return and would be clobbered by late-landing loads).
__device__ __forceinline__ void wait_tags(const unsigned int* tags, unsigned int target){
  if (threadIdx.x < 64){
    const unsigned int* p = tags + threadIdx.x * 128;
    unsigned int a0,a1,a2,a3,b0,b1,b2,b3;
    asm volatile("global_load_dword %0, %4, off sc0 sc1\n\t"
                 "global_load_dword %1, %4, off offset:128 sc0 sc1\n\t"
                 "global_load_dword %2, %4, off offset:256 sc0 sc1\n\t"
                 "global_load_dword %3, %4, off offset:384 sc0 sc1"
                 : "=v"(a0), "=v"(a1), "=v"(a2), "=v"(a3) : "v"(p) : "memory");
    asm volatile("global_load_dword %0, %4, off sc0 sc1\n\t"
                 "global_load_dword %1, %4, off offset:128 sc0 sc1\n\t"
                 "global_load_dword %2, %4, off offset:256 sc0 sc1\n\t"
                 "global_load_dword %3, %4, off offset:384 sc0 sc1"
                 : "=v"(b0), "=v"(b1), "=v"(b2), "=v"(b3) : "v"(p) : "memory");
    for (;;){
      asm volatile("s_waitcnt vmcnt(4)" ::: "memory");   // group A retired
      __builtin_amdgcn_sched_barrier(0);
      if (__all((int)(a0 >= target && a1 >= target && a2 >= target && a3 >= target))) break;
      asm volatile("global_load_dword %0, %4, off sc0 sc1\n\t"
                   "global_load_dword %1, %4, off offset:128 sc0 sc1\n\t"
                   "global_load_dword %2, %4, off offset:256 sc0 sc1\n\t"
                   "global_load_dword %3, %4, off offset:384 sc0 sc1"
                   : "=v"(a0), "=v"(a1), "=v"(a2), "=v"(a3) : "v"(p) : "memory");
      asm volatile("s_waitcnt vmcnt(4)" ::: "memory");   // group B retired
      __builtin_amdgcn_sched_barrier(0);
      if (__all((int)(b0 >= target && b1 >= target && b2 >= target && b3 >= target))) break;
      asm volatile("global_load_dword %0, %4, off sc0 sc1\n\t"
                   "global_load_dword %1, %4, off offset:128 sc0 sc1\n\t"
                   "global_load_dword %2, %4, off offset:256 sc0 sc1\n\t"
                   "global_load_dword %3, %4, off offset:384 sc0 sc1"
                   : "=v"(b0), "=v"(b1), "=v"(b2), "=v"(b3) : "v"(p) : "memory");
    }
    asm volatile("s_waitcnt vmcnt(0)" ::: "memory");     // drain stale in-flight loads
    __builtin_amdgcn_sched_barrier(0);
  }
  __syncthreads();
}

// ---------------- fused f32 -> bf16 conversion (weights + x + y in one launch) ----------------
struct CvtArgs { const float* src[17]; };

__global__ void cvt_all(CvtArgs a, unsigned short* wdst, unsigned short* xdst, unsigned short* ydst){
  const long NG = 2572288;  // (16384000 + 2*2097152) / 8
  for (long g = blockIdx.x*blockDim.x + threadIdx.x; g < NG; g += (long)gridDim.x*blockDim.x){
    long i = g * 8;
    const float* s; unsigned short* d;
    if      (i < 393216)  { s=a.src[0]+i;             d=wdst+i; }
    else if (i < 3538944) { s=a.src[1]+(i-393216);    d=wdst+i; }
    else if (i < 7077888) { s=a.src[2]+(i-3538944);   d=wdst+i; }
    else if (i < 10223616){ s=a.src[3]+(i-7077888);   d=wdst+i; }
    else if (i < 11272192){ s=a.src[4]+(i-10223616);  d=wdst+i; }
    else if (i < 12320768){ s=a.src[5]+(i-11272192);  d=wdst+i; }
    else if (i < 12451840){ s=a.src[6]+(i-12320768);  d=wdst+i; }
    else if (i < 12582912){ s=a.src[7]+(i-12451840);  d=wdst+i; }
    else if (i < 13631488){ s=a.src[8]+(i-12582912);  d=wdst+i; }
    else if (i < 13762560){ s=a.src[9]+(i-13631488);  d=wdst+i; }
    else if (i < 13893632){ s=a.src[10]+(i-13762560); d=wdst+i; }
    else if (i < 15073280){ s=a.src[11]+(i-13893632); d=wdst+i; }
    else if (i < 16121856){ s=a.src[12]+(i-15073280); d=wdst+i; }
    else if (i < 16252928){ s=a.src[13]+(i-16121856); d=wdst+i; }
    else if (i < 16384000){ s=a.src[14]+(i-16252928); d=wdst+i; }
    else if (i < 18481152){ s=a.src[15]+(i-16384000); d=xdst+(i-16384000); }
    else                  { s=a.src[16]+(i-18481152); d=ydst+(i-18481152); }
    float4 v0 = *(const float4*)s;
    float4 v1 = *(const float4*)(s + 4);
    u32x4 o;
    o.x = (unsigned int)f2bf(v0.x) | ((unsigned int)f2bf(v0.y) << 16);
    o.y = (unsigned int)f2bf(v0.z) | ((unsigned int)f2bf(v0.w) << 16);
    o.z = (unsigned int)f2bf(v1.x) | ((unsigned int)f2bf(v1.y) << 16);
    o.w = (unsigned int)f2bf(v1.z) | ((unsigned int)f2bf(v1.w) << 16);
    *(u32x4*)d = o;
  }
}

// ---------------- generic bf16 MFMA GEMM (global_load_lds staging, [128][32] linear LDS) ----
template<int ACT, int OUT_BF, int BIAS>
__launch_bounds__(256)
__global__ void gemm_bf16(const unsigned short* __restrict__ A1, int rev1, int K1,
                          const unsigned short* __restrict__ A2, int rev2, int K,
                          const unsigned short* __restrict__ W,
                          const float* __restrict__ bias,
                          void* __restrict__ Cv, int N, int m0)
{
  __shared__ __align__(16) unsigned short As[128][32];
  __shared__ __align__(16) unsigned short Ws[128][32];
  const int tid   = threadIdx.x;
  const int mbase = blockIdx.y * 128;
  const int nbase = blockIdx.x * 128;
  const int wid = tid >> 6, lane = tid & 63;
  const int wr = wid >> 1, wc = wid & 1;
  const int fr = lane & 15;
  const int kc = (lane >> 4) * 8;
  const int K2 = K - K1;
  const int nk = K >> 5;
  const int srow = lane >> 2;          // row within 16-row group (0..15)
  const int scol = (lane & 3) * 8;     // elem offset of this lane's 16B unit

  f32x4 acc[4][4];
  #pragma unroll
  for (int i = 0; i < 4; ++i)
    #pragma unroll
    for (int j = 0; j < 4; ++j)
      acc[i][j] = (f32x4){0.f, 0.f, 0.f, 0.f};

  for (int ks = 0; ks < nk; ++ks){
    const int k0 = ks << 5;
    __syncthreads();
    // stage A + W tiles via async global->LDS (wave-linear dest, per-lane source)
    #pragma unroll
    for (int i = 0; i < 2; ++i){
      const int rbase = (wid*2 + i) * 16;
      {
        int row = rbase + srow;
        int m = m0 + mbase + row;
        int kk = k0 + scol;
        const unsigned short* src;
        if (kk < K1){
          int mm = rev1 ? (((255 - (m >> 6)) << 6) | (m & 63)) : m;
          src = A1 + (size_t)mm * K1 + kk;
        } else {
          int mm = rev2 ? (((255 - (m >> 6)) << 6) | (m & 63)) : m;
          src = A2 + (size_t)mm * K2 + (kk - K1);
        }
        gload_lds16(src, &As[rbase][0]);
      }
      {
        const unsigned short* src = W + (size_t)(nbase + rbase + srow) * K + k0 + scol;
        gload_lds16(src, &Ws[rbase][0]);
      }
    }
    __syncthreads();
    bf16x8 af[4], bfm[4];
    #pragma unroll
    for (int f = 0; f < 4; ++f) af[f]  = *(const bf16x8*)&As[wr*64 + f*16 + fr][kc];
    #pragma unroll
    for (int f = 0; f < 4; ++f) bfm[f] = *(const bf16x8*)&Ws[wc*64 + f*16 + fr][kc];
    #pragma unroll
    for (int i = 0; i < 4; ++i)
      #pragma unroll
      for (int j = 0; j < 4; ++j)
        acc[i][j] = __builtin_amdgcn_mfma_f32_16x16x32_bf16(af[i], bfm[j], acc[i][j], 0, 0, 0);
  }

  #pragma unroll
  for (int i = 0; i < 4; ++i){
    #pragma unroll
    for (int j = 0; j < 4; ++j){
      #pragma unroll
      for (int r = 0; r < 4; ++r){
        int row = mbase + wr*64 + i*16 + (lane >> 4)*4 + r;
        int col = nbase + wc*64 + j*16 + fr;
        float v = acc[i][j][r];
        if (BIAS) v += bias[col];
        if (ACT == 1) v = fmaxf(v, 0.f);
        else if (ACT == 2) v = 1.f / (1.f + expf(-v));
        else if (ACT == 3) v = (v > 20.f) ? v : log1pf(expf(v));
        if (OUT_BF) ((unsigned short*)Cv)[(size_t)row * N + col] = f2bf(v);
        else        ((float*)Cv)[(size_t)row * N + col] = v;
      }
    }
  }
}

// ---------------- dual thin GEMM (64-row tiles, grid (2, 256)): two N=128 GEMMs ----------------
template<int ACTA, int ACTB>
__launch_bounds__(256)
__global__ void gemm_dual(const unsigned short* __restrict__ A,
                          const unsigned short* __restrict__ Wa, const float* __restrict__ ba,
                          float* __restrict__ Ca,
                          const unsigned short* __restrict__ Wb, const float* __restrict__ bb,
                          float* __restrict__ Cb)
{
  const unsigned short* W = blockIdx.x ? Wb : Wa;
  const float* bias = blockIdx.x ? bb : ba;
  float* C = blockIdx.x ? Cb : Ca;
  const int act = blockIdx.x ? ACTB : ACTA;

  __shared__ __align__(16) unsigned short As[64][40];
  __shared__ __align__(16) unsigned short Ws[128][40];
  const int tid   = threadIdx.x;
  const int mbase = blockIdx.y * 64;
  const int wid = tid >> 6, lane = tid & 63;
  const int fr = lane & 15, q = lane >> 4;
  const int kc = q * 8;

  f32x4 acc[8];
  #pragma unroll
  for (int j = 0; j < 8; ++j) acc[j] = (f32x4){0.f, 0.f, 0.f, 0.f};

  for (int ks = 0; ks < 32; ++ks){
    const int k0 = ks << 5;
    __syncthreads();
    if (tid < 256){
      int row = tid >> 2, c = tid & 3;
      *(uint4*)&As[row][c*8] = *(const uint4*)(A + (size_t)(mbase + row) * HD + k0 + c*8);
    }
    for (int l = tid; l < 512; l += 256){
      int row = l >> 2, c = l & 3;
      *(uint4*)&Ws[row][c*8] = *(const uint4*)(W + (size_t)row * HD + k0 + c*8);
    }
    __syncthreads();
    bf16x8 af = *(const bf16x8*)&As[wid*16 + fr][kc];
    #pragma unroll
    for (int j = 0; j < 8; ++j){
      bf16x8 bfm = *(const bf16x8*)&Ws[j*16 + fr][kc];
      acc[j] = __builtin_amdgcn_mfma_f32_16x16x32_bf16(af, bfm, acc[j], 0, 0, 0);
    }
  }

  #pragma unroll
  for (int j = 0; j < 8; ++j){
    #pragma unroll
    for (int r = 0; r < 4; ++r){
      int row = mbase + wid*16 + q*4 + r;
      int col = j*16 + fr;
      float v = acc[j][r] + bias[col];
      if (act == 1) v = fmaxf(v, 0.f);
      else if (act == 2) v = 1.f / (1.f + expf(-v));
      else if (act == 3) v = (v > 20.f) ? v : log1pf(expf(v));
      C[(size_t)row * ZD + col] = v;
    }
  }
}

// ---------------- gi-GEMM tile body (for the fat kernel; reg-staged) ----------------
__device__ void gemm_gi_tile(char* smem,
                             const unsigned short* __restrict__ A1, int rev1, int K1,
                             const unsigned short* __restrict__ A2, int rev2, int K,
                             const unsigned short* __restrict__ W,
                             unsigned short* __restrict__ C, int m0, int bx, int by)
{
  unsigned short (*As)[40] = (unsigned short(*)[40])smem;
  unsigned short (*Ws)[40] = (unsigned short(*)[40])(smem + 10240);
  const int tid   = threadIdx.x;
  const int mbase = by * 128;
  const int nbase = bx * 128;
  const int wid = tid >> 6, lane = tid & 63;
  const int wr = wid >> 1, wc = wid & 1;
  const int fr = lane & 15;
  const int kc = (lane >> 4) * 8;
  const int K2 = K - K1;
  const int nk = K >> 5;

  f32x4 acc[4][4];
  #pragma unroll
  for (int i = 0; i < 4; ++i)
    #pragma unroll
    for (int j = 0; j < 4; ++j)
      acc[i][j] = (f32x4){0.f, 0.f, 0.f, 0.f};

  for (int ks = 0; ks < nk; ++ks){
    const int k0 = ks << 5;
    __syncthreads();
    for (int l = tid; l < 512; l += 256){
      int row = l >> 2, c = l & 3;
      int kk = k0 + c*8;
      int m = m0 + mbase + row;
      uint4 v;
      if (kk < K1){
        int mm = rev1 ? (((255 - (m >> 6)) << 6) | (m & 63)) : m;
        v = *(const uint4*)(A1 + (size_t)mm * K1 + kk);
      } else {
        int mm = rev2 ? (((255 - (m >> 6)) << 6) | (m & 63)) : m;
        v = *(const uint4*)(A2 + (size_t)mm * K2 + (kk - K1));
      }
      *(uint4*)&As[row][c*8] = v;
    }
    for (int l = tid; l < 512; l += 256){
      int row = l >> 2, c = l & 3;
      uint4 v = *(const uint4*)(W + (size_t)(nbase + row) * K + k0 + c*8);
      *(uint4*)&Ws[row][c*8] = v;
    }
    __syncthreads();
    bf16x8 af[4], bfm[4];
    #pragma unroll
    for (int f = 0; f < 4; ++f) af[f]  = *(const bf16x8*)&As[wr*64 + f*16 + fr][kc];
    #pragma unroll
    for (int f = 0; f < 4; ++f) bfm[f] = *(const bf16x8*)&Ws[wc*64 + f*16 + fr][kc];
    #pragma unroll
    for (int i = 0; i < 4; ++i)
      #pragma unroll
      for (int j = 0; j < 4; ++j)
        acc[i][j] = __builtin_amdgcn_mfma_f32_16x16x32_bf16(af[i], bfm[j], acc[i][j], 0, 0, 0);
  }

  #pragma unroll
  for (int i = 0; i < 4; ++i){
    #pragma unroll
    for (int j = 0; j < 4; ++j){
      #pragma unroll
      for (int r = 0; r < 4; ++r){
        int row = mbase + wr*64 + i*16 + (lane >> 4)*4 + r;
        int col = nbase + wc*64 + j*16 + fr;
        C[(size_t)row * H3 + col] = f2bf(acc[i][j][r]);
      }
    }
  }
  __syncthreads();
}

// ---------------- persistent GRU body (64 blocks of a launch) ----------------
// Publish: each wave, after its own vwait(0), lane0 atomically sets its tag in its
// OWN 128B sector (tags[bid*128 + wid*32]) -- no block-wide join on the publish path
// (r14's same-sector RMW serialization avoided). hb2 reuse is fenced by wait_tags'
// trailing __syncthreads plus the pre-exchange __syncthreads.
__device__ void gru_body(char* smem,
                         const unsigned short* __restrict__ W3,
                         const unsigned short* __restrict__ gi,   // [nsteps][64][3072]
                         unsigned short* __restrict__ seq,
                         float* __restrict__ hstate,
                         unsigned int* __restrict__ tags,         // 64 x 4 tags, 128B sectors
                         int t0, int dir, int out_off, int nsteps)
{
  uint4 (*Wf)[3][64] = (uint4(*)[3][64])smem;                       // 96KB
  unsigned short (*hb2)[16] = (unsigned short(*)[16])(smem + 98304);// 2KB
  const int tid  = threadIdx.x;
  const int bid  = blockIdx.x;
  const int c0   = bid * 16;
  const int wid  = tid >> 6, lane = tid & 63;
  const int fr   = lane & 15, q = lane >> 4;
  const int rowb = wid*16 + q*4;
  const int arow = wid*16 + fr;

  for (int ks = wid*8; ks < wid*8 + 8; ++ks)
    #pragma unroll
    for (int g = 0; g < 3; ++g)
      Wf[ks][g][lane] = *(const uint4*)(W3 + (size_t)(g*HD + c0 + fr)*HD + ks*32 + q*8);

  float hc[4];
  if (t0 == 0){
    hc[0] = hc[1] = hc[2] = hc[3] = 0.f;
  } else {
    #pragma unroll
    for (int r = 0; r < 4; ++r)
      hc[r] = hstate[(size_t)(rowb + r)*HD + c0 + fr];
  }
  __syncthreads();

  for (int tt = 0; tt < nsteps; ++tt){
    const int t = t0 + tt;

    // gate inputs for THIS step: issue early (plain loads, overlap the tag poll)
    unsigned short g_ir[4], g_iz[4], g_in[4];
    {
      const unsigned short* gb = gi + (size_t)tt*NB*H3;
      #pragma unroll
      for (int r = 0; r < 4; ++r){
        const unsigned short* p = gb + (size_t)(rowb + r)*H3 + c0 + fr;
        g_ir[r] = p[0];
        g_iz[r] = p[HD];
        g_in[r] = p[2*HD];
      }
    }

    f32x4 aR = (f32x4){0.f,0.f,0.f,0.f};
    f32x4 aZ = (f32x4){0.f,0.f,0.f,0.f};
    f32x4 aN = (f32x4){0.f,0.f,0.f,0.f};

    if (t > 0){
      if (tt >= 1) wait_tags(tags, (unsigned int)tt);
      const unsigned short* hp = seq + (size_t)(out_off + dir*(t-1))*NB*HD
                                     + (size_t)arow*HD + q*8;
      // issue ALL 32 fragment loads; consume in 4 batches with counted vmcnt
      u32x4 A[32];
      #pragma unroll
      for (int ks = 0; ks < 32; ++ks)
        asm volatile("global_load_dwordx4 %0, %1, off offset:%2"
                     : "=v"(A[ks]) : "v"(hp), "i"(ks*64));
      #pragma unroll
      for (int b4 = 0; b4 < 4; ++b4){
        if (b4 == 0) vwait<24>();
        else if (b4 == 1) vwait<16>();
        else if (b4 == 2) vwait<8>();
        else vwait<0>();
        #pragma unroll
        for (int k8 = 0; k8 < 8; ++k8){
          const int ks = b4*8 + k8;
          bf16x8 a = *(const bf16x8*)&A[ks];
          aR = __builtin_amdgcn_mfma_f32_16x16x32_bf16(a, *(const bf16x8*)&Wf[ks][0][lane], aR, 0, 0, 0);
          aZ = __builtin_amdgcn_mfma_f32_16x16x32_bf16(a, *(const bf16x8*)&Wf[ks][1][lane], aZ, 0, 0, 0);
          aN = __builtin_amdgcn_mfma_f32_16x16x32_bf16(a, *(const bf16x8*)&Wf[ks][2][lane], aN, 0, 0, 0);
        }
      }
    }

    // gate math (fp32, in-register) -> LDS transpose buffer
    #pragma unroll
    for (int r = 0; r < 4; ++r){
      float rr = fsigmoid(bf2f(g_ir[r]) + aR[r]);
      float zz = fsigmoid(bf2f(g_iz[r]) + aZ[r]);
      float nn = ftanh(bf2f(g_in[r]) + rr * aN[r]);
      hc[r] = (1.f - zz) * nn + zz * hc[r];
      hb2[rowb + r][fr] = f2bf(hc[r]);
    }
    __syncthreads();
    // h out: 256 threads x 8B device-scope atomic exchange (performed at L3)
    {
      int row = tid >> 2, c4 = (tid & 3) * 4;
      unsigned long long v = *(const unsigned long long*)&hb2[row][c4];
      unsigned long long* dst = (unsigned long long*)(seq + (size_t)(out_off + dir*t)*NB*HD
                                                          + (size_t)row*HD + c0 + c4);
      (void)__hip_atomic_exchange(dst, v, __ATOMIC_RELAXED, __HIP_MEMORY_SCOPE_AGENT);
    }
    if (tt < nsteps - 1){
      vwait<0>();                 // THIS WAVE's atomics performed at coherence point
      if (lane == 0)
        (void)__hip_atomic_exchange(tags + bid*128 + wid*32, (unsigned int)(tt + 1),
                                    __ATOMIC_RELAXED, __HIP_MEMORY_SCOPE_AGENT);
    }
  }

  #pragma unroll
  for (int r = 0; r < 4; ++r)
    hstate[(size_t)(rowb + r)*HD + c0 + fr] = hc[r];
}

// ---------------- standalone GRU kernel (64 blocks) ----------------
__global__ __launch_bounds__(256, 1)
void gru_seq(const unsigned short* __restrict__ W3, const unsigned short* __restrict__ gi,
             unsigned short* __restrict__ seq, float* __restrict__ hstate,
             unsigned int* __restrict__ tags, int t0, int dir, int out_off, int nsteps)
{
  __shared__ __align__(16) char smem[100608];
  gru_body(smem, W3, gi, seq, hstate, tags, t0, dir, out_off, nsteps);
}

// ---------------- fat kernel: GRU quarter (blocks 0-63) + next quarter's gi GEMM (64-159) ----
__global__ __launch_bounds__(256, 1)
void gru_fat(const unsigned short* __restrict__ W3, const unsigned short* __restrict__ gi,
             unsigned short* __restrict__ seq, float* __restrict__ hstate,
             unsigned int* __restrict__ tags, int t0, int dir, int out_off, int nsteps,
             const unsigned short* __restrict__ gA1, int grev1, int gK1,
             const unsigned short* __restrict__ gA2, int grev2, int gK,
             const unsigned short* __restrict__ gW, unsigned short* __restrict__ gC, int gm0)
{
  __shared__ __align__(16) char smem[100608];
  if (blockIdx.x < 64){
    gru_body(smem, W3, gi, seq, hstate, tags, t0, dir, out_off, nsteps);
  } else {
    for (int tl = blockIdx.x - 64; tl < 768; tl += 96)   // (24 nx) x (32 my) tiles
      gemm_gi_tile(smem, gA1, grev1, gK1, gA2, grev2, gK, gW, gC, gm0, tl % 24, tl / 24);
  }
}

// ---------------- z = eps*enc_std + enc_mean (bf16 out) ----------------
__global__ void z_make(const float* __restrict__ eps, const float* __restrict__ em,
                       const float* __restrict__ es, unsigned short* __restrict__ zb, int n){
  for (int i = blockIdx.x*blockDim.x + threadIdx.x; i < n; i += gridDim.x*blockDim.x)
    zb[i] = f2bf(eps[i] * es[i] + em[i]);
}

// ---------------- reductions ----------------
__global__ void kld_partial(const float* __restrict__ em, const float* __restrict__ es,
                            const float* __restrict__ pm, const float* __restrict__ ps,
                            float* __restrict__ part, int n){
  float s = 0.f;
  for (int i = blockIdx.x*blockDim.x + threadIdx.x; i < n; i += gridDim.x*blockDim.x){
    float e = es[i], p = ps[i], d = em[i] - pm[i];
    s += 2.f*(logf(p) - logf(e)) + (e*e + d*d)/(p*p) - 1.f;
  }
  __shared__ float red[256];
  red[threadIdx.x] = s; __syncthreads();
  for (int off = 128; off; off >>= 1){
    if (threadIdx.x < off) red[threadIdx.x] += red[threadIdx.x + off];
    __syncthreads();
  }
  if (threadIdx.x == 0) part[blockIdx.x] = red[0];
}

__global__ void nll_partial(const float* __restrict__ y, const float* __restrict__ dm,
                            float* __restrict__ part, int n){
  float s = 0.f;
  for (int i = blockIdx.x*blockDim.x + threadIdx.x; i < n; i += gridDim.x*blockDim.x){
    float yy = y[i], d = dm[i];
    s += yy * logf(d) + (1.f - yy) * logf(1.f - d);
  }
  __shared__ float red[256];
  red[threadIdx.x] = s; __syncthreads();
  for (int off = 128; off; off >>= 1){
    if (threadIdx.x < off) red[threadIdx.x] += red[threadIdx.x + off];
    __syncthreads();
  }
  if (threadIdx.x == 0) part[blockIdx.x] = red[0];
}

__global__ void final_sum(const float* __restrict__ part, int n, float scale, float* __restrict__ out){
  float s = 0.f;
  for (int i = threadIdx.x; i < n; i += 256) s += part[i];
  __shared__ float red[256];
  red[threadIdx.x] = s; __syncthreads();
  for (int off = 128; off; off >>= 1){
    if (threadIdx.x < off) red[threadIdx.x] += red[threadIdx.x + off];
    __syncthreads();
  }
  if (threadIdx.x == 0) out[0] = scale * red[0];
}

// ---------------- host ----------------
extern "C" void kernel_launch(void* const* d_in, const int* in_sizes, int n_in,
                              void* d_out, int out_size, void* d_ws, size_t ws_size,
                              hipStream_t stream)
{
  const float* y   = (const float*)d_in[1];
  const float* eps = (const float*)d_in[2];
  const float* enc_b1 = (const float*)d_in[8];
  const float* enc_b2 = (const float*)d_in[10];
  const float* encm_b = (const float*)d_in[12];
  const float* encs_b = (const float*)d_in[14];
  const float* pr_b   = (const float*)d_in[16];
  const float* prm_b  = (const float*)d_in[18];
  const float* prs_b  = (const float*)d_in[20];
  const float* dec_b1 = (const float*)d_in[22];
  const float* dec_b2 = (const float*)d_in[24];
  const float* decm_b = (const float*)d_in[26];
  const float* decs_b = (const float*)d_in[28];

  // ---- workspace layout (~165 MiB) ----
  char* ws = (char*)d_ws;
  size_t off = 0;
  auto alloc = [&](size_t bytes){ size_t o = off; off += (bytes + 255) & ~(size_t)255; return o; };
  const size_t o_big   = alloc((size_t)71303168);       // 68 MiB phase-union region
  const size_t o_hseq  = alloc((size_t)TBM * HD * 2);   // h_seq bf16 (32 MiB)
  const size_t o_aseq  = alloc((size_t)TBM * HD * 2);   // a_fwd bf16 (32 MiB)
  const size_t o_wbf   = alloc((size_t)16384000 * 2);   // all weights bf16 (~31.3 MiB)
  const size_t o_hst   = alloc((size_t)NB * HD * 4);    // f32 h carry between quarter launches
  const size_t o_bar   = alloc((size_t)262144);         // 8 x 64 x 4 tag sectors (128B apart)
  const size_t o_pkld  = alloc((size_t)1024 * 4);
  const size_t o_pnll  = alloc((size_t)1024 * 4);
  (void)off; (void)ws_size;

  char* big = ws + o_big;
  unsigned short* gihA = (unsigned short*)(big);
  unsigned short* gihB = (unsigned short*)(big + 25165824);
  unsigned short* xbf  = (unsigned short*)(big + 50331648);
  unsigned short* ybf  = (unsigned short*)(big + 54525952);
  unsigned short* tA  = (unsigned short*)(big);
  unsigned short* tB  = (unsigned short*)(big + 33554432);
  unsigned short* zbf = (unsigned short*)(big + 67108864);

  unsigned short* hseq = (unsigned short*)(ws + o_hseq);
  unsigned short* aseq = (unsigned short*)(ws + o_aseq);
  unsigned short* wbf  = (unsigned short*)(ws + o_wbf);
  float* hstate = (float*)(ws + o_hst);
  unsigned int* bar = (unsigned int*)(ws + o_bar);
  float* pkld = (float*)(ws + o_pkld);
  float* pnll = (float*)(ws + o_pnll);

  const int widx[15] = {3,4,5,6,7,9,11,13,15,17,19,21,23,25,27};
  const size_t wsz[15] = {393216,3145728,3538944,3145728,1048576,1048576,131072,131072,
                          1048576,131072,131072,1179648,1048576,131072,131072};
  size_t woff[15]; { size_t a = 0; for (int i = 0; i < 15; ++i){ woff[i] = a; a += wsz[i]; } }
  unsigned short* w_hWih = wbf + woff[0];
  unsigned short* w_hWhh = wbf + woff[1];
  unsigned short* w_aWih = wbf + woff[2];
  unsigned short* w_aWhh = wbf + woff[3];
  unsigned short* w_enc1 = wbf + woff[4];
  unsigned short* w_enc2 = wbf + woff[5];
  unsigned short* w_encm = wbf + woff[6];
  unsigned short* w_encs = wbf + woff[7];
  unsigned short* w_pr   = wbf + woff[8];
  unsigned short* w_prm  = wbf + woff[9];
  unsigned short* w_prs  = wbf + woff[10];
  unsigned short* w_dec1 = wbf + woff[11];
  unsigned short* w_dec2 = wbf + woff[12];
  unsigned short* w_decm = wbf + woff[13];
  unsigned short* w_decs = wbf + woff[14];

  float* out = (float*)d_out;
  float* em_out = out + 2;
  float* es_out = out + 2 + 2097152;
  float* dm_out = out + 2 + 2*2097152;   // doubles as pm scratch before decoder
  float* ds_out = out + 2 + 3*2097152;   // doubles as ps scratch before decoder
  float* pm = dm_out;
  float* ps = ds_out;

  // --- fused converts + tag init ---
  CvtArgs ca;
  for (int i = 0; i < 15; ++i) ca.src[i] = (const float*)d_in[widx[i]];
  ca.src[15] = (const float*)d_in[0];   // x
  ca.src[16] = (const float*)d_in[1];   // y
  cvt_all<<<2048, 256, 0, stream>>>(ca, wbf, xbf, ybf);
  (void)hipMemsetAsync(bar, 0, 262144, stream);

  const dim3 blk(256);
  const dim3 gQ3072(24, 32);            // 4096-row quarter of the gi GEMM
  const dim3 g1024(HD/128, TBM/128);
  const dim3 gDual(2, TBM/64);          // 64-row tiles -> 512 blocks
  const unsigned short* nul = (const unsigned short*)nullptr;

  // --- GRU 1: quarters; gi GEMM for quarter q+1 hidden inside the fat kernel ---
  gemm_bf16<0,1,0><<<gQ3072, blk, 0, stream>>>(xbf, 0, XD, nul, 0, XD, w_hWih, nullptr, gihA, H3, 0);
  gru_fat<<<160, blk, 0, stream>>>(w_hWhh, gihA, hseq, hstate, bar + 0*8192, 0,   +1, 0, 64,
                                   xbf, 0, XD, nul, 0, XD, w_hWih, gihB, 4096);
  gru_fat<<<160, blk, 0, stream>>>(w_hWhh, gihB, hseq, hstate, bar + 1*8192, 64,  +1, 0, 64,
                                   xbf, 0, XD, nul, 0, XD, w_hWih, gihA, 8192);
  gru_fat<<<160, blk, 0, stream>>>(w_hWhh, gihA, hseq, hstate, bar + 2*8192, 128, +1, 0, 64,
                                   xbf, 0, XD, nul, 0, XD, w_hWih, gihB, 12288);
  gru_seq<<<64, blk, 0, stream>>>(w_hWhh, gihB, hseq, hstate, bar + 3*8192, 192, +1, 0, 64);

  // --- GRU 2: input [y_rev | h_rev]; output written reversed => a_fwd ---
  gemm_bf16<0,1,0><<<gQ3072, blk, 0, stream>>>(ybf, 1, XD, hseq, 1, XD + HD, w_aWih, nullptr, gihA, H3, 0);
  gru_fat<<<160, blk, 0, stream>>>(w_aWhh, gihA, aseq, hstate, bar + 4*8192, 0,   -1, 255, 64,
                                   ybf, 1, XD, hseq, 1, XD + HD, w_aWih, gihB, 4096);
  gru_fat<<<160, blk, 0, stream>>>(w_aWhh, gihB, aseq, hstate, bar + 5*8192, 64,  -1, 255, 64,
                                   ybf, 1, XD, hseq, 1, XD + HD, w_aWih, gihA, 8192);
  gru_fat<<<160, blk, 0, stream>>>(w_aWhh, gihA, aseq, hstate, bar + 6*8192, 128, -1, 255, 64,
                                   ybf, 1, XD, hseq, 1, XD + HD, w_aWih, gihB, 12288);
  gru_seq<<<64, blk, 0, stream>>>(w_aWhh, gihB, aseq, hstate, bar + 7*8192, 192, -1, 255, 64);

  // --- encoder ---
  gemm_bf16<1,1,1><<<g1024, blk, 0, stream>>>(aseq, 0, HD, nul, 0, HD, w_enc1, enc_b1, tA, HD, 0);
  gemm_bf16<1,1,1><<<g1024, blk, 0, stream>>>(tA, 0, HD, nul, 0, HD, w_enc2, enc_b2, tB, HD, 0);
  gemm_dual<0,3><<<gDual, blk, 0, stream>>>(tB, w_encm, encm_b, em_out, w_encs, encs_b, es_out);
  z_make<<<2048, 256, 0, stream>>>(eps, em_out, es_out, zbf, TBM*ZD);

  // --- prior (pm/ps into dm/ds regions; kld BEFORE decoder overwrites them) ---
  gemm_bf16<1,1,1><<<g1024, blk, 0, stream>>>(hseq, 1, HD, nul, 1, HD, w_pr, pr_b, tA, HD, 0);
  gemm_dual<0,3><<<gDual, blk, 0, stream>>>(tA, w_prm, prm_b, pm, w_prs, prs_b, ps);
  kld_partial<<<1024, 256, 0, stream>>>(em_out, es_out, pm, ps, pkld, TBM*ZD);
  final_sum<<<1, 256, 0, stream>>>(pkld, 1024, 0.5f, out + 0);

  // --- decoder ---
  gemm_bf16<1,1,1><<<g1024, blk, 0, stream>>>(zbf, 0, ZD, hseq, 1, ZD + HD, w_dec1, dec_b1, tA, HD, 0);
  gemm_bf16<1,1,1><<<g1024, blk, 0, stream>>>(tA, 0, HD, nul, 0, HD, w_dec2, dec_b2, tB, HD, 0);
  gemm_dual<2,3><<<gDual, blk, 0, stream>>>(tB, w_decm, decm_b, dm_out, w_decs, decs_b, ds_out);

  // --- nll ---
  nll_partial<<<1024, 256, 0, stream>>>(y, dm_out, pnll, TBM*XD);
  final_sum<<<1, 256, 0, stream>>>(pnll, 1024, -1.0f, out + 1);
}

// Round 19
// 4292.141 us; speedup vs baseline: 1.0554x; 1.0554x over previous
//
#include <hip/hip_runtime.h>
#include <cstdint>
#include <cstddef>

// Problem dims
#define NT   256     // T
#define NB   64      // B
#define XD   128
#define HD   1024
#define ZD   128
#define H3   3072
#define TBM  16384   // T*B

typedef __attribute__((ext_vector_type(8))) short bf16x8;
typedef __attribute__((ext_vector_type(4))) float f32x4;
typedef __attribute__((ext_vector_type(4))) unsigned int u32x4;

__device__ __forceinline__ unsigned short f2bf(float f){
  unsigned int u = __float_as_uint(f);
  u += 0x7fffu + ((u >> 16) & 1u);
  return (unsigned short)(u >> 16);
}
__device__ __forceinline__ float bf2f(unsigned short h){
  return __uint_as_float(((unsigned int)h) << 16);
}

template<int N>
__device__ __forceinline__ void vwait(){
  asm volatile("s_waitcnt vmcnt(%0)" :: "i"(N) : "memory");
  __builtin_amdgcn_sched_barrier(0);
}

// async global->LDS, 16B per lane; dest = wave-uniform base + lane*16
__device__ __forceinline__ void gload_lds16(const void* g, void* l){
  __builtin_amdgcn_global_load_lds((const __attribute__((address_space(1))) void*)g,
                                   (__attribute__((address_space(3))) void*)l, 16, 0, 0);
}

// fast gates
__device__ __forceinline__ float fsigmoid(float x){
  return 1.f / (1.f + __expf(-x));
}
__device__ __forceinline__ float ftanh(float x){
  float xc = fminf(fmaxf(x, -15.f), 15.f);
  float e = __expf(2.f * xc);
  return (e - 1.f) / (e + 1.f);
}

// wave0 polls 64 tags (one per block, 128B apart) with a 2-deep pipelined ping-pong:
// one tag load always in flight while the other is checked. Drain vmcnt(0) before
// return (r12 lesson: in-flight load's dest VGPR gets reused and would be clobbered).
__device__ __forceinline__ void wait_tags(const unsigned int* tags, unsigned int target){
  if (threadIdx.x < 64){
    const unsigned int* p = tags + threadIdx.x * 32;   // 128B spacing
    unsigned int a, b;
    asm volatile("global_load_dword %0, %2, off sc0 sc1\n\t"
                 "global_load_dword %1, %2, off sc0 sc1"
                 : "=v"(a), "=v"(b) : "v"(p) : "memory");
    for (;;){
      asm volatile("s_waitcnt vmcnt(1)" ::: "memory");   // oldest retired
      __builtin_amdgcn_sched_barrier(0);
      if (__all((int)(a >= target))) break;
      asm volatile("global_load_dword %0, %1, off sc0 sc1" : "=v"(a) : "v"(p) : "memory");
      asm volatile("s_waitcnt vmcnt(1)" ::: "memory");
      __builtin_amdgcn_sched_barrier(0);
      if (__all((int)(b >= target))) break;
      asm volatile("global_load_dword %0, %1, off sc0 sc1" : "=v"(b) : "v"(p) : "memory");
    }
    asm volatile("s_waitcnt vmcnt(0)" ::: "memory");     // drain stale in-flight load
    __builtin_amdgcn_sched_barrier(0);
  }
  __syncthreads();
}

// ---------------- fused f32 -> bf16 conversion (weights + x + y in one launch) ----------------
struct CvtArgs { const float* src[17]; };

__global__ void cvt_all(CvtArgs a, unsigned short* wdst, unsigned short* xdst, unsigned short* ydst){
  const long NG = 2572288;  // (16384000 + 2*2097152) / 8
  for (long g = blockIdx.x*blockDim.x + threadIdx.x; g < NG; g += (long)gridDim.x*blockDim.x){
    long i = g * 8;
    const float* s; unsigned short* d;
    if      (i < 393216)  { s=a.src[0]+i;             d=wdst+i; }
    else if (i < 3538944) { s=a.src[1]+(i-393216);    d=wdst+i; }
    else if (i < 7077888) { s=a.src[2]+(i-3538944);   d=wdst+i; }
    else if (i < 10223616){ s=a.src[3]+(i-7077888);   d=wdst+i; }
    else if (i < 11272192){ s=a.src[4]+(i-10223616);  d=wdst+i; }
    else if (i < 12320768){ s=a.src[5]+(i-11272192);  d=wdst+i; }
    else if (i < 12451840){ s=a.src[6]+(i-12320768);  d=wdst+i; }
    else if (i < 12582912){ s=a.src[7]+(i-12451840);  d=wdst+i; }
    else if (i < 13631488){ s=a.src[8]+(i-12582912);  d=wdst+i; }
    else if (i < 13762560){ s=a.src[9]+(i-13631488);  d=wdst+i; }
    else if (i < 13893632){ s=a.src[10]+(i-13762560); d=wdst+i; }
    else if (i < 15073280){ s=a.src[11]+(i-13893632); d=wdst+i; }
    else if (i < 16121856){ s=a.src[12]+(i-15073280); d=wdst+i; }
    else if (i < 16252928){ s=a.src[13]+(i-16121856); d=wdst+i; }
    else if (i < 16384000){ s=a.src[14]+(i-16252928); d=wdst+i; }
    else if (i < 18481152){ s=a.src[15]+(i-16384000); d=xdst+(i-16384000); }
    else                  { s=a.src[16]+(i-18481152); d=ydst+(i-18481152); }
    float4 v0 = *(const float4*)s;
    float4 v1 = *(const float4*)(s + 4);
    u32x4 o;
    o.x = (unsigned int)f2bf(v0.x) | ((unsigned int)f2bf(v0.y) << 16);
    o.y = (unsigned int)f2bf(v0.z) | ((unsigned int)f2bf(v0.w) << 16);
    o.z = (unsigned int)f2bf(v1.x) | ((unsigned int)f2bf(v1.y) << 16);
    o.w = (unsigned int)f2bf(v1.z) | ((unsigned int)f2bf(v1.w) << 16);
    *(u32x4*)d = o;
  }
}

// ---------------- generic bf16 MFMA GEMM (global_load_lds staging, [128][32] linear LDS) ----
template<int ACT, int OUT_BF, int BIAS>
__launch_bounds__(256)
__global__ void gemm_bf16(const unsigned short* __restrict__ A1, int rev1, int K1,
                          const unsigned short* __restrict__ A2, int rev2, int K,
                          const unsigned short* __restrict__ W,
                          const float* __restrict__ bias,
                          void* __restrict__ Cv, int N, int m0)
{
  __shared__ __align__(16) unsigned short As[128][32];
  __shared__ __align__(16) unsigned short Ws[128][32];
  const int tid   = threadIdx.x;
  const int mbase = blockIdx.y * 128;
  const int nbase = blockIdx.x * 128;
  const int wid = tid >> 6, lane = tid & 63;
  const int wr = wid >> 1, wc = wid & 1;
  const int fr = lane & 15;
  const int kc = (lane >> 4) * 8;
  const int K2 = K - K1;
  const int nk = K >> 5;
  const int srow = lane >> 2;          // row within 16-row group (0..15)
  const int scol = (lane & 3) * 8;     // elem offset of this lane's 16B unit

  f32x4 acc[4][4];
  #pragma unroll
  for (int i = 0; i < 4; ++i)
    #pragma unroll
    for (int j = 0; j < 4; ++j)
      acc[i][j] = (f32x4){0.f, 0.f, 0.f, 0.f};

  for (int ks = 0; ks < nk; ++ks){
    const int k0 = ks << 5;
    __syncthreads();
    // stage A + W tiles via async global->LDS (wave-linear dest, per-lane source)
    #pragma unroll
    for (int i = 0; i < 2; ++i){
      const int rbase = (wid*2 + i) * 16;
      {
        int row = rbase + srow;
        int m = m0 + mbase + row;
        int kk = k0 + scol;
        const unsigned short* src;
        if (kk < K1){
          int mm = rev1 ? (((255 - (m >> 6)) << 6) | (m & 63)) : m;
          src = A1 + (size_t)mm * K1 + kk;
        } else {
          int mm = rev2 ? (((255 - (m >> 6)) << 6) | (m & 63)) : m;
          src = A2 + (size_t)mm * K2 + (kk - K1);
        }
        gload_lds16(src, &As[rbase][0]);
      }
      {
        const unsigned short* src = W + (size_t)(nbase + rbase + srow) * K + k0 + scol;
        gload_lds16(src, &Ws[rbase][0]);
      }
    }
    __syncthreads();
    bf16x8 af[4], bfm[4];
    #pragma unroll
    for (int f = 0; f < 4; ++f) af[f]  = *(const bf16x8*)&As[wr*64 + f*16 + fr][kc];
    #pragma unroll
    for (int f = 0; f < 4; ++f) bfm[f] = *(const bf16x8*)&Ws[wc*64 + f*16 + fr][kc];
    #pragma unroll
    for (int i = 0; i < 4; ++i)
      #pragma unroll
      for (int j = 0; j < 4; ++j)
        acc[i][j] = __builtin_amdgcn_mfma_f32_16x16x32_bf16(af[i], bfm[j], acc[i][j], 0, 0, 0);
  }

  #pragma unroll
  for (int i = 0; i < 4; ++i){
    #pragma unroll
    for (int j = 0; j < 4; ++j){
      #pragma unroll
      for (int r = 0; r < 4; ++r){
        int row = mbase + wr*64 + i*16 + (lane >> 4)*4 + r;
        int col = nbase + wc*64 + j*16 + fr;
        float v = acc[i][j][r];
        if (BIAS) v += bias[col];
        if (ACT == 1) v = fmaxf(v, 0.f);
        else if (ACT == 2) v = 1.f / (1.f + expf(-v));
        else if (ACT == 3) v = (v > 20.f) ? v : log1pf(expf(v));
        if (OUT_BF) ((unsigned short*)Cv)[(size_t)row * N + col] = f2bf(v);
        else        ((float*)Cv)[(size_t)row * N + col] = v;
      }
    }
  }
}

// ---------------- dual thin GEMM (64-row tiles, grid (2, 256)): two N=128 GEMMs ----------------
template<int ACTA, int ACTB>
__launch_bounds__(256)
__global__ void gemm_dual(const unsigned short* __restrict__ A,
                          const unsigned short* __restrict__ Wa, const float* __restrict__ ba,
                          float* __restrict__ Ca,
                          const unsigned short* __restrict__ Wb, const float* __restrict__ bb,
                          float* __restrict__ Cb)
{
  const unsigned short* W = blockIdx.x ? Wb : Wa;
  const float* bias = blockIdx.x ? bb : ba;
  float* C = blockIdx.x ? Cb : Ca;
  const int act = blockIdx.x ? ACTB : ACTA;

  __shared__ __align__(16) unsigned short As[64][40];
  __shared__ __align__(16) unsigned short Ws[128][40];
  const int tid   = threadIdx.x;
  const int mbase = blockIdx.y * 64;
  const int wid = tid >> 6, lane = tid & 63;
  const int fr = lane & 15, q = lane >> 4;
  const int kc = q * 8;

  f32x4 acc[8];
  #pragma unroll
  for (int j = 0; j < 8; ++j) acc[j] = (f32x4){0.f, 0.f, 0.f, 0.f};

  for (int ks = 0; ks < 32; ++ks){
    const int k0 = ks << 5;
    __syncthreads();
    if (tid < 256){
      int row = tid >> 2, c = tid & 3;
      *(uint4*)&As[row][c*8] = *(const uint4*)(A + (size_t)(mbase + row) * HD + k0 + c*8);
    }
    for (int l = tid; l < 512; l += 256){
      int row = l >> 2, c = l & 3;
      *(uint4*)&Ws[row][c*8] = *(const uint4*)(W + (size_t)row * HD + k0 + c*8);
    }
    __syncthreads();
    bf16x8 af = *(const bf16x8*)&As[wid*16 + fr][kc];
    #pragma unroll
    for (int j = 0; j < 8; ++j){
      bf16x8 bfm = *(const bf16x8*)&Ws[j*16 + fr][kc];
      acc[j] = __builtin_amdgcn_mfma_f32_16x16x32_bf16(af, bfm, acc[j], 0, 0, 0);
    }
  }

  #pragma unroll
  for (int j = 0; j < 8; ++j){
    #pragma unroll
    for (int r = 0; r < 4; ++r){
      int row = mbase + wid*16 + q*4 + r;
      int col = j*16 + fr;
      float v = acc[j][r] + bias[col];
      if (act == 1) v = fmaxf(v, 0.f);
      else if (act == 2) v = 1.f / (1.f + expf(-v));
      else if (act == 3) v = (v > 20.f) ? v : log1pf(expf(v));
      C[(size_t)row * ZD + col] = v;
    }
  }
}

// ---------------- gi-GEMM tile body (for the fat kernel; reg-staged) ----------------
__device__ void gemm_gi_tile(char* smem,
                             const unsigned short* __restrict__ A1, int rev1, int K1,
                             const unsigned short* __restrict__ A2, int rev2, int K,
                             const unsigned short* __restrict__ W,
                             unsigned short* __restrict__ C, int m0, int bx, int by)
{
  unsigned short (*As)[40] = (unsigned short(*)[40])smem;
  unsigned short (*Ws)[40] = (unsigned short(*)[40])(smem + 10240);
  const int tid   = threadIdx.x;
  const int mbase = by * 128;
  const int nbase = bx * 128;
  const int wid = tid >> 6, lane = tid & 63;
  const int wr = wid >> 1, wc = wid & 1;
  const int fr = lane & 15;
  const int kc = (lane >> 4) * 8;
  const int K2 = K - K1;
  const int nk = K >> 5;

  f32x4 acc[4][4];
  #pragma unroll
  for (int i = 0; i < 4; ++i)
    #pragma unroll
    for (int j = 0; j < 4; ++j)
      acc[i][j] = (f32x4){0.f, 0.f, 0.f, 0.f};

  for (int ks = 0; ks < nk; ++ks){
    const int k0 = ks << 5;
    __syncthreads();
    for (int l = tid; l < 512; l += 256){
      int row = l >> 2, c = l & 3;
      int kk = k0 + c*8;
      int m = m0 + mbase + row;
      uint4 v;
      if (kk < K1){
        int mm = rev1 ? (((255 - (m >> 6)) << 6) | (m & 63)) : m;
        v = *(const uint4*)(A1 + (size_t)mm * K1 + kk);
      } else {
        int mm = rev2 ? (((255 - (m >> 6)) << 6) | (m & 63)) : m;
        v = *(const uint4*)(A2 + (size_t)mm * K2 + (kk - K1));
      }
      *(uint4*)&As[row][c*8] = v;
    }
    for (int l = tid; l < 512; l += 256){
      int row = l >> 2, c = l & 3;
      uint4 v = *(const uint4*)(W + (size_t)(nbase + row) * K + k0 + c*8);
      *(uint4*)&Ws[row][c*8] = v;
    }
    __syncthreads();
    bf16x8 af[4], bfm[4];
    #pragma unroll
    for (int f = 0; f < 4; ++f) af[f]  = *(const bf16x8*)&As[wr*64 + f*16 + fr][kc];
    #pragma unroll
    for (int f = 0; f < 4; ++f) bfm[f] = *(const bf16x8*)&Ws[wc*64 + f*16 + fr][kc];
    #pragma unroll
    for (int i = 0; i < 4; ++i)
      #pragma unroll
      for (int j = 0; j < 4; ++j)
        acc[i][j] = __builtin_amdgcn_mfma_f32_16x16x32_bf16(af[i], bfm[j], acc[i][j], 0, 0, 0);
  }

  #pragma unroll
  for (int i = 0; i < 4; ++i){
    #pragma unroll
    for (int j = 0; j < 4; ++j){
      #pragma unroll
      for (int r = 0; r < 4; ++r){
        int row = mbase + wr*64 + i*16 + (lane >> 4)*4 + r;
        int col = nbase + wc*64 + j*16 + fr;
        C[(size_t)row * H3 + col] = f2bf(acc[i][j][r]);
      }
    }
  }
  __syncthreads();
}

// ---------------- persistent GRU body (64 blocks of a launch; round-13 sync) ----------------
__device__ void gru_body(char* smem,
                         const unsigned short* __restrict__ W3,
                         const unsigned short* __restrict__ gi,   // [nsteps][64][3072]
                         unsigned short* __restrict__ seq,
                         float* __restrict__ hstate,
                         unsigned int* __restrict__ tags,         // 64 tags, 128B apart
                         int t0, int dir, int out_off, int nsteps)
{
  uint4 (*Wf)[3][64] = (uint4(*)[3][64])smem;                       // 96KB
  unsigned short (*hb2)[16] = (unsigned short(*)[16])(smem + 98304);// 2KB
  const int tid  = threadIdx.x;
  const int bid  = blockIdx.x;
  const int c0   = bid * 16;
  const int wid  = tid >> 6, lane = tid & 63;
  const int fr   = lane & 15, q = lane >> 4;
  const int rowb = wid*16 + q*4;
  const int arow = wid*16 + fr;

  for (int ks = wid*8; ks < wid*8 + 8; ++ks)
    #pragma unroll
    for (int g = 0; g < 3; ++g)
      Wf[ks][g][lane] = *(const uint4*)(W3 + (size_t)(g*HD + c0 + fr)*HD + ks*32 + q*8);

  float hc[4];
  if (t0 == 0){
    hc[0] = hc[1] = hc[2] = hc[3] = 0.f;
  } else {
    #pragma unroll
    for (int r = 0; r < 4; ++r)
      hc[r] = hstate[(size_t)(rowb + r)*HD + c0 + fr];
  }
  __syncthreads();

  for (int tt = 0; tt < nsteps; ++tt){
    const int t = t0 + tt;

    // gate inputs for THIS step: issue early (plain loads, overlap the tag poll)
    unsigned short g_ir[4], g_iz[4], g_in[4];
    {
      const unsigned short* gb = gi + (size_t)tt*NB*H3;
      #pragma unroll
      for (int r = 0; r < 4; ++r){
        const unsigned short* p = gb + (size_t)(rowb + r)*H3 + c0 + fr;
        g_ir[r] = p[0];
        g_iz[r] = p[HD];
        g_in[r] = p[2*HD];
      }
    }

    f32x4 aR = (f32x4){0.f,0.f,0.f,0.f};
    f32x4 aZ = (f32x4){0.f,0.f,0.f,0.f};
    f32x4 aN = (f32x4){0.f,0.f,0.f,0.f};

    if (t > 0){
      if (tt >= 1) wait_tags(tags, (unsigned int)tt);
      const unsigned short* hp = seq + (size_t)(out_off + dir*(t-1))*NB*HD
                                     + (size_t)arow*HD + q*8;
      // issue ALL 32 fragment loads; consume in 4 batches with counted vmcnt
      u32x4 A[32];
      #pragma unroll
      for (int ks = 0; ks < 32; ++ks)
        asm volatile("global_load_dwordx4 %0, %1, off offset:%2"
                     : "=v"(A[ks]) : "v"(hp), "i"(ks*64));
      #pragma unroll
      for (int b4 = 0; b4 < 4; ++b4){
        if (b4 == 0) vwait<24>();
        else if (b4 == 1) vwait<16>();
        else if (b4 == 2) vwait<8>();
        else vwait<0>();
        #pragma unroll
        for (int k8 = 0; k8 < 8; ++k8){
          const int ks = b4*8 + k8;
          bf16x8 a = *(const bf16x8*)&A[ks];
          aR = __builtin_amdgcn_mfma_f32_16x16x32_bf16(a, *(const bf16x8*)&Wf[ks][0][lane], aR, 0, 0, 0);
          aZ = __builtin_amdgcn_mfma_f32_16x16x32_bf16(a, *(const bf16x8*)&Wf[ks][1][lane], aZ, 0, 0, 0);
          aN = __builtin_amdgcn_mfma_f32_16x16x32_bf16(a, *(const bf16x8*)&Wf[ks][2][lane], aN, 0, 0, 0);
        }
      }
    }

    // gate math (fp32, in-register) -> LDS transpose buffer
    #pragma unroll
    for (int r = 0; r < 4; ++r){
      float rr = fsigmoid(bf2f(g_ir[r]) + aR[r]);
      float zz = fsigmoid(bf2f(g_iz[r]) + aZ[r]);
      float nn = ftanh(bf2f(g_in[r]) + rr * aN[r]);
      hc[r] = (1.f - zz) * nn + zz * hc[r];
      hb2[rowb + r][fr] = f2bf(hc[r]);
    }
    __syncthreads();
    // h out: 256 threads x 8B device-scope atomic exchange (performed at L3)
    {
      int row = tid >> 2, c4 = (tid & 3) * 4;
      unsigned long long v = *(const unsigned long long*)&hb2[row][c4];
      unsigned long long* dst = (unsigned long long*)(seq + (size_t)(out_off + dir*t)*NB*HD
                                                          + (size_t)row*HD + c0 + c4);
      (void)__hip_atomic_exchange(dst, v, __ATOMIC_RELAXED, __HIP_MEMORY_SCOPE_AGENT);
    }
    if (tt < nsteps - 1){
      vwait<0>();                 // own atomics performed at coherence point
      __syncthreads();            // all lanes done
      if (tid == 0)
        (void)__hip_atomic_exchange(tags + bid*32, (unsigned int)(tt + 1),
                                    __ATOMIC_RELAXED, __HIP_MEMORY_SCOPE_AGENT);
    }
  }

  #pragma unroll
  for (int r = 0; r < 4; ++r)
    hstate[(size_t)(rowb + r)*HD + c0 + fr] = hc[r];
}

// ---------------- standalone GRU kernel (64 blocks) ----------------
__global__ __launch_bounds__(256, 1)
void gru_seq(const unsigned short* __restrict__ W3, const unsigned short* __restrict__ gi,
             unsigned short* __restrict__ seq, float* __restrict__ hstate,
             unsigned int* __restrict__ tags, int t0, int dir, int out_off, int nsteps)
{
  __shared__ __align__(16) char smem[100608];
  gru_body(smem, W3, gi, seq, hstate, tags, t0, dir, out_off, nsteps);
}

// ---------------- fat kernel: GRU quarter (blocks 0-63) + next quarter's gi GEMM (64-159) ----
__global__ __launch_bounds__(256, 1)
void gru_fat(const unsigned short* __restrict__ W3, const unsigned short* __restrict__ gi,
             unsigned short* __restrict__ seq, float* __restrict__ hstate,
             unsigned int* __restrict__ tags, int t0, int dir, int out_off, int nsteps,
             const unsigned short* __restrict__ gA1, int grev1, int gK1,
             const unsigned short* __restrict__ gA2, int grev2, int gK,
             const unsigned short* __restrict__ gW, unsigned short* __restrict__ gC, int gm0)
{
  __shared__ __align__(16) char smem[100608];
  if (blockIdx.x < 64){
    gru_body(smem, W3, gi, seq, hstate, tags, t0, dir, out_off, nsteps);
  } else {
    for (int tl = blockIdx.x - 64; tl < 768; tl += 96)   // (24 nx) x (32 my) tiles
      gemm_gi_tile(smem, gA1, grev1, gK1, gA2, grev2, gK, gW, gC, gm0, tl % 24, tl / 24);
  }
}

// ---------------- z = eps*enc_std + enc_mean (bf16 out) ----------------
__global__ void z_make(const float* __restrict__ eps, const float* __restrict__ em,
                       const float* __restrict__ es, unsigned short* __restrict__ zb, int n){
  for (int i = blockIdx.x*blockDim.x + threadIdx.x; i < n; i += gridDim.x*blockDim.x)
    zb[i] = f2bf(eps[i] * es[i] + em[i]);
}

// ---------------- reductions ----------------
__global__ void kld_partial(const float* __restrict__ em, const float* __restrict__ es,
                            const float* __restrict__ pm, const float* __restrict__ ps,
                            float* __restrict__ part, int n){
  float s = 0.f;
  for (int i = blockIdx.x*blockDim.x + threadIdx.x; i < n; i += gridDim.x*blockDim.x){
    float e = es[i], p = ps[i], d = em[i] - pm[i];
    s += 2.f*(logf(p) - logf(e)) + (e*e + d*d)/(p*p) - 1.f;
  }
  __shared__ float red[256];
  red[threadIdx.x] = s; __syncthreads();
  for (int off = 128; off; off >>= 1){
    if (threadIdx.x < off) red[threadIdx.x] += red[threadIdx.x + off];
    __syncthreads();
  }
  if (threadIdx.x == 0) part[blockIdx.x] = red[0];
}

__global__ void nll_partial(const float* __restrict__ y, const float* __restrict__ dm,
                            float* __restrict__ part, int n){
  float s = 0.f;
  for (int i = blockIdx.x*blockDim.x + threadIdx.x; i < n; i += gridDim.x*blockDim.x){
    float yy = y[i], d = dm[i];
    s += yy * logf(d) + (1.f - yy) * logf(1.f - d);
  }
  __shared__ float red[256];
  red[threadIdx.x] = s; __syncthreads();
  for (int off = 128; off; off >>= 1){
    if (threadIdx.x < off) red[threadIdx.x] += red[threadIdx.x + off];
    __syncthreads();
  }
  if (threadIdx.x == 0) part[blockIdx.x] = red[0];
}

__global__ void final_sum(const float* __restrict__ part, int n, float scale, float* __restrict__ out){
  float s = 0.f;
  for (int i = threadIdx.x; i < n; i += 256) s += part[i];
  __shared__ float red[256];
  red[threadIdx.x] = s; __syncthreads();
  for (int off = 128; off; off >>= 1){
    if (threadIdx.x < off) red[threadIdx.x] += red[threadIdx.x + off];
    __syncthreads();
  }
  if (threadIdx.x == 0) out[0] = scale * red[0];
}

// ---------------- host ----------------
extern "C" void kernel_launch(void* const* d_in, const int* in_sizes, int n_in,
                              void* d_out, int out_size, void* d_ws, size_t ws_size,
                              hipStream_t stream)
{
  const float* y   = (const float*)d_in[1];
  const float* eps = (const float*)d_in[2];
  const float* enc_b1 = (const float*)d_in[8];
  const float* enc_b2 = (const float*)d_in[10];
  const float* encm_b = (const float*)d_in[12];
  const float* encs_b = (const float*)d_in[14];
  const float* pr_b   = (const float*)d_in[16];
  const float* prm_b  = (const float*)d_in[18];
  const float* prs_b  = (const float*)d_in[20];
  const float* dec_b1 = (const float*)d_in[22];
  const float* dec_b2 = (const float*)d_in[24];
  const float* decm_b = (const float*)d_in[26];
  const float* decs_b = (const float*)d_in[28];

  // ---- workspace layout (~164 MiB) ----
  char* ws = (char*)d_ws;
  size_t off = 0;
  auto alloc = [&](size_t bytes){ size_t o = off; off += (bytes + 255) & ~(size_t)255; return o; };
  const size_t o_big   = alloc((size_t)71303168);       // 68 MiB phase-union region
  const size_t o_hseq  = alloc((size_t)TBM * HD * 2);   // h_seq bf16 (32 MiB)
  const size_t o_aseq  = alloc((size_t)TBM * HD * 2);   // a_fwd bf16 (32 MiB)
  const size_t o_wbf   = alloc((size_t)16384000 * 2);   // all weights bf16 (~31.3 MiB)
  const size_t o_hst   = alloc((size_t)NB * HD * 4);    // f32 h carry between quarter launches
  const size_t o_bar   = alloc((size_t)65536);          // 8 x 64 tag sectors (128B apart)
  const size_t o_pkld  = alloc((size_t)1024 * 4);
  const size_t o_pnll  = alloc((size_t)1024 * 4);
  (void)off; (void)ws_size;

  char* big = ws + o_big;
  unsigned short* gihA = (unsigned short*)(big);
  unsigned short* gihB = (unsigned short*)(big + 25165824);
  unsigned short* xbf  = (unsigned short*)(big + 50331648);
  unsigned short* ybf  = (unsigned short*)(big + 54525952);
  unsigned short* tA  = (unsigned short*)(big);
  unsigned short* tB  = (unsigned short*)(big + 33554432);
  unsigned short* zbf = (unsigned short*)(big + 67108864);

  unsigned short* hseq = (unsigned short*)(ws + o_hseq);
  unsigned short* aseq = (unsigned short*)(ws + o_aseq);
  unsigned short* wbf  = (unsigned short*)(ws + o_wbf);
  float* hstate = (float*)(ws + o_hst);
  unsigned int* bar = (unsigned int*)(ws + o_bar);
  float* pkld = (float*)(ws + o_pkld);
  float* pnll = (float*)(ws + o_pnll);

  const int widx[15] = {3,4,5,6,7,9,11,13,15,17,19,21,23,25,27};
  const size_t wsz[15] = {393216,3145728,3538944,3145728,1048576,1048576,131072,131072,
                          1048576,131072,131072,1179648,1048576,131072,131072};
  size_t woff[15]; { size_t a = 0; for (int i = 0; i < 15; ++i){ woff[i] = a; a += wsz[i]; } }
  unsigned short* w_hWih = wbf + woff[0];
  unsigned short* w_hWhh = wbf + woff[1];
  unsigned short* w_aWih = wbf + woff[2];
  unsigned short* w_aWhh = wbf + woff[3];
  unsigned short* w_enc1 = wbf + woff[4];
  unsigned short* w_enc2 = wbf + woff[5];
  unsigned short* w_encm = wbf + woff[6];
  unsigned short* w_encs = wbf + woff[7];
  unsigned short* w_pr   = wbf + woff[8];
  unsigned short* w_prm  = wbf + woff[9];
  unsigned short* w_prs  = wbf + woff[10];
  unsigned short* w_dec1 = wbf + woff[11];
  unsigned short* w_dec2 = wbf + woff[12];
  unsigned short* w_decm = wbf + woff[13];
  unsigned short* w_decs = wbf + woff[14];

  float* out = (float*)d_out;
  float* em_out = out + 2;
  float* es_out = out + 2 + 2097152;
  float* dm_out = out + 2 + 2*2097152;   // doubles as pm scratch before decoder
  float* ds_out = out + 2 + 3*2097152;   // doubles as ps scratch before decoder
  float* pm = dm_out;
  float* ps = ds_out;

  // --- fused converts + tag init ---
  CvtArgs ca;
  for (int i = 0; i < 15; ++i) ca.src[i] = (const float*)d_in[widx[i]];
  ca.src[15] = (const float*)d_in[0];   // x
  ca.src[16] = (const float*)d_in[1];   // y
  cvt_all<<<2048, 256, 0, stream>>>(ca, wbf, xbf, ybf);
  (void)hipMemsetAsync(bar, 0, 65536, stream);

  const dim3 blk(256);
  const dim3 gQ3072(24, 32);            // 4096-row quarter of the gi GEMM
  const dim3 g1024(HD/128, TBM/128);
  const dim3 gDual(2, TBM/64);          // 64-row tiles -> 512 blocks
  const unsigned short* nul = (const unsigned short*)nullptr;

  // --- GRU 1: quarters; gi GEMM for quarter q+1 hidden inside the fat kernel ---
  gemm_bf16<0,1,0><<<gQ3072, blk, 0, stream>>>(xbf, 0, XD, nul, 0, XD, w_hWih, nullptr, gihA, H3, 0);
  gru_fat<<<160, blk, 0, stream>>>(w_hWhh, gihA, hseq, hstate, bar + 0*2048, 0,   +1, 0, 64,
                                   xbf, 0, XD, nul, 0, XD, w_hWih, gihB, 4096);
  gru_fat<<<160, blk, 0, stream>>>(w_hWhh, gihB, hseq, hstate, bar + 1*2048, 64,  +1, 0, 64,
                                   xbf, 0, XD, nul, 0, XD, w_hWih, gihA, 8192);
  gru_fat<<<160, blk, 0, stream>>>(w_hWhh, gihA, hseq, hstate, bar + 2*2048, 128, +1, 0, 64,
                                   xbf, 0, XD, nul, 0, XD, w_hWih, gihB, 12288);
  gru_seq<<<64, blk, 0, stream>>>(w_hWhh, gihB, hseq, hstate, bar + 3*2048, 192, +1, 0, 64);

  // --- GRU 2: input [y_rev | h_rev]; output written reversed => a_fwd ---
  gemm_bf16<0,1,0><<<gQ3072, blk, 0, stream>>>(ybf, 1, XD, hseq, 1, XD + HD, w_aWih, nullptr, gihA, H3, 0);
  gru_fat<<<160, blk, 0, stream>>>(w_aWhh, gihA, aseq, hstate, bar + 4*2048, 0,   -1, 255, 64,
                                   ybf, 1, XD, hseq, 1, XD + HD, w_aWih, gihB, 4096);
  gru_fat<<<160, blk, 0, stream>>>(w_aWhh, gihB, aseq, hstate, bar + 5*2048, 64,  -1, 255, 64,
                                   ybf, 1, XD, hseq, 1, XD + HD, w_aWih, gihA, 8192);
  gru_fat<<<160, blk, 0, stream>>>(w_aWhh, gihA, aseq, hstate, bar + 6*2048, 128, -1, 255, 64,
                                   ybf, 1, XD, hseq, 1, XD + HD, w_aWih, gihB, 12288);
  gru_seq<<<64, blk, 0, stream>>>(w_aWhh, gihB, aseq, hstate, bar + 7*2048, 192, -1, 255, 64);

  // --- encoder ---
  gemm_bf16<1,1,1><<<g1024, blk, 0, stream>>>(aseq, 0, HD, nul, 0, HD, w_enc1, enc_b1, tA, HD, 0);
  gemm_bf16<1,1,1><<<g1024, blk, 0, stream>>>(tA, 0, HD, nul, 0, HD, w_enc2, enc_b2, tB, HD, 0);
  gemm_dual<0,3><<<gDual, blk, 0, stream>>>(tB, w_encm, encm_b, em_out, w_encs, encs_b, es_out);
  z_make<<<2048, 256, 0, stream>>>(eps, em_out, es_out, zbf, TBM*ZD);

  // --- prior (pm/ps into dm/ds regions; kld BEFORE decoder overwrites them) ---
  gemm_bf16<1,1,1><<<g1024, blk, 0, stream>>>(hseq, 1, HD, nul, 1, HD, w_pr, pr_b, tA, HD, 0);
  gemm_dual<0,3><<<gDual, blk, 0, stream>>>(tA, w_prm, prm_b, pm, w_prs, prs_b, ps);
  kld_partial<<<1024, 256, 0, stream>>>(em_out, es_out, pm, ps, pkld, TBM*ZD);
  final_sum<<<1, 256, 0, stream>>>(pkld, 1024, 0.5f, out + 0);

  // --- decoder ---
  gemm_bf16<1,1,1><<<g1024, blk, 0, stream>>>(zbf, 0, ZD, hseq, 1, ZD + HD, w_dec1, dec_b1, tA, HD, 0);
  gemm_bf16<1,1,1><<<g1024, blk, 0, stream>>>(tA, 0, HD, nul, 0, HD, w_dec2, dec_b2, tB, HD, 0);
  gemm_dual<2,3><<<gDual, blk, 0, stream>>>(tB, w_decm, decm_b, dm_out, w_decs, decs_b, ds_out);

  // --- nll ---
  nll_partial<<<1024, 256, 0, stream>>>(y, dm_out, pnll, TBM*XD);
  final_sum<<<1, 256, 0, stream>>>(pnll, 1024, -1.0f, out + 1);
}